// Round 10
// baseline (279.374 us; speedup 1.0000x reference)
//
#include <hip/hip_runtime.h>
#include <hip/hip_bf16.h>

typedef __bf16 bf16x8 __attribute__((ext_vector_type(8)));
typedef int   i32x8  __attribute__((ext_vector_type(8)));
typedef float f32x4  __attribute__((ext_vector_type(4)));
typedef float f32x16 __attribute__((ext_vector_type(16)));

#define KDIM 512
#define NDIM 1024
#define DDIM 256
#define TDIM 512
#define MDIM 2048
#define NROWS 16384          // B*T type_flat rows
#define NEGV -1e10f
#define NLM 128              // lm blocks fused at the front of the main grid
#define WARR 524288          // byte offset of V-array in permuted weights

__device__ __forceinline__ unsigned int pk8(float a, float b, float c, float d) {
    unsigned int p = (unsigned int)__builtin_amdgcn_cvt_pk_fp8_f32(a, b, 0, 0);
    return (unsigned int)__builtin_amdgcn_cvt_pk_fp8_f32(c, d, (int)p, 1);
}

typedef const __attribute__((address_space(1))) unsigned int* gas_p;
typedef __attribute__((address_space(3))) unsigned int* las_p;
__device__ __forceinline__ void gl2lds16(const void* g, void* l) {
    __builtin_amdgcn_global_load_lds((gas_p)g, (las_p)l, 16, 0, 0);
}

// ---------------------------------------------------------------------------
// prep_all — R27: roles 1/3 as R26 (neutral but compact).  Role 2 REWRITTEN:
// wp8 is now permuted for 32x32x64 f8f6f4 fragments — frag32 keyed
// (n32 = n>>5, k64 = k>>6), 2048 B each at offset (n32*8+k64)*2048; within a
// frag lane l = (n&31) + 32*((k>>5)&1) holds bytes [l*32 .. l*32+32) =
// B[n32*32 + (l&31)][k64*64 + (l>>5)*32 + b].
// ---------------------------------------------------------------------------
__global__ void prep_all(const float* __restrict__ tok,
                         const float* __restrict__ Wg,
                         const float* __restrict__ Wv,
                         const int* __restrict__ bp,
                         unsigned char* __restrict__ tf8,
                         unsigned char* __restrict__ wp8,
                         int* __restrict__ counts,
                         unsigned short* __restrict__ lists) {
    const int bid = blockIdx.x;
    const int tid = threadIdx.x;
    if (bid == 0) {
        // ---- role 3: per-batch m-lists ----
        __shared__ int c[32];
        if (tid < 32) c[tid] = 0;
        __syncthreads();
        for (int m = tid; m < MDIM; m += 256) {
            int b = bp[m];
            int pos = atomicAdd(&c[b], 1);
            lists[b * MDIM + pos] = (unsigned short)m;
        }
        __syncthreads();
        if (tid < 32) counts[tid] = c[tid];
    } else if (bid <= 512) {
        // ---- role 2: weight transpose+quant into 32x32x64 fragment order ----
        __shared__ float tg[32][33];
        __shared__ float tv[32][33];
        int pb = bid - 1;
        int n0 = (pb & 31) * 32, k0 = (pb >> 5) * 32;
        {
            int kk = tid >> 3, nn = (tid & 7) * 4;
            float4 g = *(const float4*)(Wg + (size_t)(k0 + kk) * NDIM + n0 + nn);
            float4 v = *(const float4*)(Wv + (size_t)(k0 + kk) * NDIM + n0 + nn);
            tg[kk][nn] = g.x; tg[kk][nn + 1] = g.y; tg[kk][nn + 2] = g.z; tg[kk][nn + 3] = g.w;
            tv[kk][nn] = v.x; tv[kk][nn + 1] = v.y; tv[kk][nn + 2] = v.z; tv[kk][nn + 3] = v.w;
        }
        __syncthreads();
        int nn2 = tid >> 3, kk2 = (tid & 7) * 4;
        unsigned int pg = pk8(tg[kk2][nn2], tg[kk2 + 1][nn2],
                              tg[kk2 + 2][nn2], tg[kk2 + 3][nn2]);
        unsigned int pv = pk8(tv[kk2][nn2], tv[kk2 + 1][nn2],
                              tv[kk2 + 2][nn2], tv[kk2 + 3][nn2]);
        // frag32 mapping: n = n0+nn2, k = k0+kk2 (4 consecutive k bytes)
        int n32 = pb & 31;            // n0/32
        int k64 = pb >> 6;            // k0/64
        int khalf = (pb >> 5) & 1;    // (k0>>5)&1
        size_t off = (size_t)(n32 * 8 + k64) * 2048
                   + (size_t)(khalf * 32 + nn2) * 32 + kk2;
        *(unsigned int*)(wp8 + off) = pg;
        *(unsigned int*)(wp8 + WARR + off) = pv;
    } else {
        // ---- role 1: type_flat fp32 -> fp8 quant, 16 elems/thread ----
        int g = ((bid - 513) * 256 + tid) * 16;
        int i = g >> 8, c = g & 255;
        const float* src = tok + (size_t)i * 1024 + c;
        unsigned int d[4];
#pragma unroll
        for (int j = 0; j < 4; j++) {
            float4 v = *(const float4*)(src + j * 4);
            d[j] = pk8(v.x, v.y, v.z, v.w);
        }
        uint4 o; o.x = d[0]; o.y = d[1]; o.z = d[2]; o.w = d[3];
        *(uint4*)(tf8 + g) = o;
    }
}

// ---------------------------------------------------------------------------
// fused_main — R27: lemma GEMM moved from 16x16x128 to 32x32x64 MFMA shape.
// Same tile (M=128, per-nt N=64), same 4-wave wm/wn split, same barrier-free
// K-loop, same 1-step B register double-buffer, same staging volume (64 KB),
// same epilogue math.  What changes: per kc-step 8 MFMAs of 2x duration
// instead of 16 -> half the vmcnt/lgkmcnt dependency joints (the candidate
// for the ~43% neither-pipe cycles); acc regs 128 -> 64 (2mi x f32x16 x 2),
// lem 16 -> 32, net demand DROPS ~48 vs the proven-fitting baseline.
// Layouts (verified mappings, cdna4 guide m74/m101):
//   A frag: row = lane&31, k = (lane>>5)*32 + byte   (LDS region (g,k64), 2KB)
//   B frag: col = lane&31, k = (lane>>5)*32 + byte   (wp8 frag32, prep role 2)
//   C/D:    col = lane&31, row = (reg&3) + 8*(reg>>2) + 4*(lane>>5)
// SESSION LEDGER (R18-R26, counter-verified): occupancy is NOT the limit
// (R23 3-wave no-spill neutral); caps <=170 spill catastrophically
// (R18/19/20/24: 64-260MB scratch); s_setprio poisons hipcc scheduling
// (R22 isolated, +27MB scratch); manual af pipelining neutral (R21);
// prep_all/grid reorg neutral (R26 — non-fused ~86us is harness-fixed).
// lm path (blocks < NLM) byte-identical to the verified best.
// ---------------------------------------------------------------------------
__launch_bounds__(256, 2)
__global__ void fused_main(const unsigned char* __restrict__ tf8,
                           const unsigned char* __restrict__ wp8,
                           const float* __restrict__ Wo,
                           const int* __restrict__ scope,
                           const int* __restrict__ goal,
                           float* __restrict__ outLem, int E,
                           const float* __restrict__ tok,
                           const int* __restrict__ lmi,
                           const int* __restrict__ counts,
                           const unsigned short* __restrict__ lists,
                           const int* __restrict__ tpm,
                           float* __restrict__ outP) {
    __shared__ unsigned char sA[64 * 1024];   // 32 regions x 2 KB, key (g, k64)
    __shared__ float sRed[256];

    const int tid = threadIdx.x;
    const int lane = tid & 63;
    const int w = tid >> 6;
    const int col = lane & 15;
    const int q = lane >> 4;
    const int ln32 = lane & 31;    // row/col within 32
    const int q2 = lane >> 5;      // k-half selector

    if ((int)blockIdx.x < NLM) {
        // ------------- lm_preds gather-GEMM, MX-fp8 (R14-proven) -------------
        const int lb = blockIdx.x;
        const int b = lb & 31;
        const int t0 = (lb >> 5) * 128;
        const int cnt = counts[b];
        for (int mt = w * 16; mt < cnt; mt += 64) {
            int mc = mt + col;
            int aid = lists[b * MDIM + (mc < cnt ? mc : cnt - 1)];
            const float* arow = tok + (size_t)lmi[aid] * DDIM;
            i32x8 af[2];
#pragma unroll
            for (int kc = 0; kc < 2; kc++) {
                unsigned int d[8];
#pragma unroll
                for (int j = 0; j < 8; j++) {
                    float4 v = *(const float4*)(arow + kc * 128 + q * 32 + j * 4);
                    d[j] = pk8(v.x, v.y, v.z, v.w);
                }
                af[kc] = (i32x8){(int)d[0], (int)d[1], (int)d[2], (int)d[3],
                                 (int)d[4], (int)d[5], (int)d[6], (int)d[7]};
            }
            int gm[4];
#pragma unroll
            for (int r = 0; r < 4; r++) {
                int mrow = mt + q * 4 + r;
                gm[r] = (mrow < cnt) ? (int)lists[b * MDIM + mrow] : -1;
            }
#pragma unroll
            for (int ntile = 0; ntile < 8; ntile++) {
                int t = t0 + ntile * 16 + col;
                const unsigned char* brow = tf8 + (size_t)(b * TDIM + t) * DDIM;
                f32x4 acc = (f32x4){0.f, 0.f, 0.f, 0.f};
#pragma unroll
                for (int kc = 0; kc < 2; kc++) {
                    uint4 lo = *(const uint4*)(brow + kc * 128 + q * 32);
                    uint4 hi = *(const uint4*)(brow + kc * 128 + q * 32 + 16);
                    i32x8 bf = (i32x8){(int)lo.x, (int)lo.y, (int)lo.z, (int)lo.w,
                                       (int)hi.x, (int)hi.y, (int)hi.z, (int)hi.w};
                    acc = __builtin_amdgcn_mfma_scale_f32_16x16x128_f8f6f4(
                        af[kc], bf, acc, 0, 0, 0, 0x7F7F7F7F, 0, 0x7F7F7F7F);
                }
                int pmv = tpm[b * TDIM + t];
#pragma unroll
                for (int r = 0; r < 4; r++) {
                    if (gm[r] >= 0)
                        outP[(size_t)gm[r] * TDIM + t] = pmv ? acc[r] : NEGV;
                }
            }
        }
        return;
    }

    // ------------------- lemma MX-fp8 GEMM, 32x32x64 fragments ---------------
    const int bx = blockIdx.x - NLM;
    const int etile = bx * 128;
    const int wm = w & 1;      // m-half (64 rows = m32-groups {2wm, 2wm+1})
    const int wn = w >> 1;     // n-half (32 of the 64-wide n-tile)

    // ---- stage A once: 32 regions x 2 KB (2 calls each), 16 calls/wave ----
#pragma unroll
    for (int i = 0; i < 16; i++) {
        int rc = w * 16 + i;          // 0..63
        int j = rc & 1;               // 16-B half within lane's 32 B
        int reg = rc >> 1;            // region 0..31
        int g = reg >> 3, k64 = reg & 7;
        int row = g * 32 + ln32;
        int e = etile + row;
        int id = (e < E) ? ((k64 < 4) ? scope[e] : goal[e]) : 0;
        gl2lds16(tf8 + (size_t)id * DDIM + (k64 & 3) * 64 + q2 * 32 + j * 16,
                 &sA[reg * 2048 + j * 1024]);
    }
    __syncthreads();   // the ONLY barrier before the reduction

    float lem[32];
#pragma unroll
    for (int i = 0; i < 32; i++) lem[i] = 0.f;

    const unsigned char* wbase = wp8 + lane * 32;

    // step s = nt*4+kc; frag32 F = nt*16 + wn*8 + kc*2 + kk
#define LOADB(s, buf)                                                          \
    {                                                                          \
        _Pragma("unroll")                                                      \
        for (int kk_ = 0; kk_ < 2; kk_++) {                                    \
            size_t f_ = (size_t)((((s) >> 2) * 16) + wn * 8 +                  \
                                 (((s) & 3) * 2) + kk_) * 2048;                \
            uint4 lo_ = *(const uint4*)(wbase + f_);                           \
            uint4 hi_ = *(const uint4*)(wbase + f_ + 16);                      \
            bgb[buf][kk_] = (i32x8){(int)lo_.x, (int)lo_.y, (int)lo_.z,        \
                (int)lo_.w, (int)hi_.x, (int)hi_.y, (int)hi_.z, (int)hi_.w};   \
            lo_ = *(const uint4*)(wbase + WARR + f_);                          \
            hi_ = *(const uint4*)(wbase + WARR + f_ + 16);                     \
            bvb[buf][kk_] = (i32x8){(int)lo_.x, (int)lo_.y, (int)lo_.z,        \
                (int)lo_.w, (int)hi_.x, (int)hi_.y, (int)hi_.z, (int)hi_.w};   \
        }                                                                      \
    }

    i32x8 bgb[2][2], bvb[2][2];
    LOADB(0, 0)

    for (int nt = 0; nt < 16; nt++) {
        f32x16 accG[2], accV[2];
#pragma unroll
        for (int mi = 0; mi < 2; mi++)
#pragma unroll
            for (int r = 0; r < 16; r++) {
                accG[mi][r] = 0.f;
                accV[mi][r] = 0.f;
            }
#pragma unroll
        for (int kc = 0; kc < 4; kc++) {
            const int cur = kc & 1, nxt = cur ^ 1;
            LOADB(nt * 4 + kc + 1, nxt)        // prefetch next step's B
#pragma unroll
            for (int mi = 0; mi < 2; mi++) {
                int rbase = (wm * 2 + mi) * 8 + kc * 2;
#pragma unroll
                for (int kk = 0; kk < 2; kk++) {
                    uint4 lo = *(const uint4*)(&sA[(rbase + kk) * 2048 + lane * 16]);
                    uint4 hi = *(const uint4*)(&sA[(rbase + kk) * 2048 + 1024 + lane * 16]);
                    i32x8 af = (i32x8){(int)lo.x, (int)lo.y, (int)lo.z, (int)lo.w,
                                       (int)hi.x, (int)hi.y, (int)hi.z, (int)hi.w};
                    accG[mi] = __builtin_amdgcn_mfma_scale_f32_32x32x64_f8f6f4(
                        af, bgb[cur][kk], accG[mi], 0, 0, 0,
                        0x7F7F7F7F, 0, 0x7F7F7F7F);
                    accV[mi] = __builtin_amdgcn_mfma_scale_f32_32x32x64_f8f6f4(
                        af, bvb[cur][kk], accV[mi], 0, 0, 0,
                        0x7F7F7F7F, 0, 0x7F7F7F7F);
                }
            }
        }
        // epilogue: lem += silu(G)*V*Wo[n].  exp+rcpf (R14-proven).
        float wo = Wo[nt * 64 + wn * 32 + ln32];
#pragma unroll
        for (int mi = 0; mi < 2; mi++)
#pragma unroll
            for (int r = 0; r < 16; r++) {
                float g = accG[mi][r];
                float v = accV[mi][r];
                float s = g * __builtin_amdgcn_rcpf(1.f + __expf(-g));
                lem[mi * 16 + r] += s * v * wo;
            }
    }
    // reduce across the 32 N-cols (q2 halves hold DIFFERENT rows -> width 32),
    // then across the 2 n-wave halves via sRed
#pragma unroll
    for (int i = 0; i < 32; i++) {
        float v = lem[i];
        for (int off = 16; off > 0; off >>= 1) v += __shfl_xor(v, off, 32);
        if (ln32 == 0) {
            int mi = i >> 4, r = i & 15;
            int row_local = (r & 3) + 8 * (r >> 2) + 4 * q2;
            sRed[wn * 128 + wm * 64 + mi * 32 + row_local] = v;
        }
    }
    __syncthreads();
    if (tid < 128) {
        int e = etile + tid;
        if (e < E) outLem[e] = sRed[tid] + sRed[128 + tid];
    }
}

extern "C" void kernel_launch(void* const* d_in, const int* in_sizes, int n_in,
                              void* d_out, int out_size, void* d_ws, size_t ws_size,
                              hipStream_t stream) {
    const float* tok = (const float*)d_in[0];
    const float* Wg  = (const float*)d_in[1];
    const float* Wv  = (const float*)d_in[2];
    const float* Wo  = (const float*)d_in[3];
    const int* edge = (const int*)d_in[4];
    const int* lmi  = (const int*)d_in[5];
    const int* bp   = (const int*)d_in[6];
    const int* tpm  = (const int*)d_in[7];
    const int E = in_sizes[4] / 2;           // 100000
    float* out = (float*)d_out;

    // workspace layout (~5.2 MB)
    unsigned char* tf8 = (unsigned char*)d_ws;                 // 4 MB
    unsigned char* wp8 = tf8 + (size_t)NROWS * DDIM;           // 1 MB (G+V)
    int* counts = (int*)(wp8 + 2 * WARR);                      // 128 B
    unsigned short* lists = (unsigned short*)(counts + 32);    // 128 KB

    prep_all<<<dim3(1537), dim3(256), 0, stream>>>(
        tok, Wg, Wv, bp, tf8, wp8, counts, lists);
    int nLemBlocks = (E + 127) / 128;        // 782
    fused_main<<<dim3(NLM + nLemBlocks), dim3(256), 0, stream>>>(
        tf8, wp8, Wo, edge, edge + E, out, E,
        tok, lmi, counts, lists, tpm, out + E);
}

// Round 11
// 229.950 us; speedup vs baseline: 1.2149x; 1.2149x over previous
//
#include <hip/hip_runtime.h>
#include <hip/hip_bf16.h>

typedef __bf16 bf16x8 __attribute__((ext_vector_type(8)));
typedef int   i32x8 __attribute__((ext_vector_type(8)));
typedef float f32x4 __attribute__((ext_vector_type(4)));

#define KDIM 512
#define NDIM 1024
#define DDIM 256
#define TDIM 512
#define MDIM 2048
#define NROWS 16384          // B*T type_flat rows
#define NEGV -1e10f
#define NLM 128              // lm blocks fused at the front of the main grid
#define WARR 524288          // byte offset of V-array in permuted weights

__device__ __forceinline__ unsigned int pk8(float a, float b, float c, float d) {
    unsigned int p = (unsigned int)__builtin_amdgcn_cvt_pk_fp8_f32(a, b, 0, 0);
    return (unsigned int)__builtin_amdgcn_cvt_pk_fp8_f32(c, d, (int)p, 1);
}

typedef const __attribute__((address_space(1))) unsigned int* gas_p;
typedef __attribute__((address_space(3))) unsigned int* las_p;
__device__ __forceinline__ void gl2lds16(const void* g, void* l) {
    __builtin_amdgcn_global_load_lds((gas_p)g, (las_p)l, 16, 0, 0);
}

// ---------------------------------------------------------------------------
// prep_all: one launch, three roles by blockIdx.  (R14/R16-proven; restored
// to the exact R25-measured-best form.  R26's reorg was neutral — the ~86us
// of non-fused time is harness reset cost, invariant to prep structure.)
// ---------------------------------------------------------------------------
__global__ void prep_all(const float* __restrict__ tok,
                         const float* __restrict__ Wg,
                         const float* __restrict__ Wv,
                         const int* __restrict__ bp,
                         unsigned char* __restrict__ tf8,
                         unsigned char* __restrict__ wp8,
                         int* __restrict__ counts,
                         unsigned short* __restrict__ lists) {
    const int bid = blockIdx.x;
    const int tid = threadIdx.x;
    if (bid < 4096) {
        int g = (bid * 256 + tid) * 4;
        int i = g >> 8, c = g & 255;
        float4 v = *(const float4*)(tok + (size_t)i * 1024 + c);
        *(unsigned int*)(tf8 + g) = pk8(v.x, v.y, v.z, v.w);
    } else if (bid < 4608) {
        __shared__ float tg[32][33];
        __shared__ float tv[32][33];
        int pb = bid - 4096;
        int n0 = (pb & 31) * 32, k0 = (pb >> 5) * 32;
        {
            int kk = tid >> 3, nn = (tid & 7) * 4;
            float4 g = *(const float4*)(Wg + (size_t)(k0 + kk) * NDIM + n0 + nn);
            float4 v = *(const float4*)(Wv + (size_t)(k0 + kk) * NDIM + n0 + nn);
            tg[kk][nn] = g.x; tg[kk][nn + 1] = g.y; tg[kk][nn + 2] = g.z; tg[kk][nn + 3] = g.w;
            tv[kk][nn] = v.x; tv[kk][nn + 1] = v.y; tv[kk][nn + 2] = v.z; tv[kk][nn + 3] = v.w;
        }
        __syncthreads();
        int nn2 = tid >> 3, kk2 = (tid & 7) * 4;
        unsigned int pg = pk8(tg[kk2][nn2], tg[kk2 + 1][nn2],
                              tg[kk2 + 2][nn2], tg[kk2 + 3][nn2]);
        unsigned int pv = pk8(tv[kk2][nn2], tv[kk2 + 1][nn2],
                              tv[kk2 + 2][nn2], tv[kk2 + 3][nn2]);
        int n = n0 + nn2, k = k0 + kk2;
        int nt = n >> 6, wn = (n >> 5) & 1, ni = (n >> 4) & 1, cp = n & 15;
        int kc = k >> 7, rem = k & 127, qq = rem >> 5, hh = (rem >> 4) & 1, bb = rem & 15;
        int frag = ((nt * 4 + kc) * 2 + wn) * 2 + ni;
        size_t off = (size_t)frag * 2048 + (qq * 16 + cp) * 32 + hh * 16 + bb;
        *(unsigned int*)(wp8 + off) = pg;
        *(unsigned int*)(wp8 + WARR + off) = pv;
    } else {
        __shared__ int c[32];
        if (tid < 32) c[tid] = 0;
        __syncthreads();
        for (int m = tid; m < MDIM; m += 256) {
            int b = bp[m];
            int pos = atomicAdd(&c[b], 1);
            lists[b * MDIM + pos] = (unsigned short)m;
        }
        __syncthreads();
        if (tid < 32) counts[tid] = c[tid];
    }
}

// ---------------------------------------------------------------------------
// fused_main — FINAL: the verified best (142.5-143.7us fused, 228.7us total;
// M=128, (256,2), barrier-free K-loop, 1-step B register double-buffer,
// fragment-ordered conflict-free staging, exp+rcpf silu).
//
// COMPLETE SESSION LEDGER (R18-R27, every axis counter-verified):
//  * Occupancy is NOT the limit: R23 hit 3 waves/SIMD with zero spill
//    (occupancy +40%) — perf NEUTRAL, MfmaUtil pinned ~31% at 2 AND 3 waves.
//  * Register cliff: any launch_bounds cap <= 170 spills catastrophically
//    (R18 80MB, R19 207MB, R20 64MB, R24 260MB scratch WRITE).  Compiler
//    scheduling slack is ~30-40 regs beyond any hand ledger.
//  * s_setprio is POISON (R22 isolated: hipcc scheduler boundary, +27MB
//    scratch, MfmaUtil 31->22).  Manual af software-pipelining neutral (R21).
//  * MFMA shape 32x32x64 is WORSE (R27, no-spill: fused 183us, MfmaUtil 23)
//    — halving instruction count doubles per-instr latency with too few
//    independent chains at 2 waves/SIMD; 16x16x128's many short MFMAs
//    schedule better at this occupancy.
//  * prep_all/launch reorg neutral (R26): the ~86us total-minus-fused block
//    is harness reset cost, invariant across all ten rounds.
// Conclusion: this configuration is the optimum of the reachable design
// space; MfmaUtil ~31% at 2 waves/SIMD is a compiler/register-file-mediated
// structural limit at HIP source level for this fused op.
// ---------------------------------------------------------------------------
__launch_bounds__(256, 2)
__global__ void fused_main(const unsigned char* __restrict__ tf8,
                           const unsigned char* __restrict__ wp8,
                           const float* __restrict__ Wo,
                           const int* __restrict__ scope,
                           const int* __restrict__ goal,
                           float* __restrict__ outLem, int E,
                           const float* __restrict__ tok,
                           const int* __restrict__ lmi,
                           const int* __restrict__ counts,
                           const unsigned short* __restrict__ lists,
                           const int* __restrict__ tpm,
                           float* __restrict__ outP) {
    __shared__ unsigned char sA[64 * 1024];   // 64 regions x 1 KB, key (am,mi,kc,j)
    __shared__ float sRed[256];

    const int tid = threadIdx.x;
    const int lane = tid & 63;
    const int w = tid >> 6;
    const int col = lane & 15;
    const int q = lane >> 4;

    if ((int)blockIdx.x < NLM) {
        // ------------- lm_preds gather-GEMM, MX-fp8 (R14-proven) -------------
        const int lb = blockIdx.x;
        const int b = lb & 31;
        const int t0 = (lb >> 5) * 128;
        const int cnt = counts[b];
        for (int mt = w * 16; mt < cnt; mt += 64) {
            int mc = mt + col;
            int aid = lists[b * MDIM + (mc < cnt ? mc : cnt - 1)];
            const float* arow = tok + (size_t)lmi[aid] * DDIM;
            i32x8 af[2];
#pragma unroll
            for (int kc = 0; kc < 2; kc++) {
                unsigned int d[8];
#pragma unroll
                for (int j = 0; j < 8; j++) {
                    float4 v = *(const float4*)(arow + kc * 128 + q * 32 + j * 4);
                    d[j] = pk8(v.x, v.y, v.z, v.w);
                }
                af[kc] = (i32x8){(int)d[0], (int)d[1], (int)d[2], (int)d[3],
                                 (int)d[4], (int)d[5], (int)d[6], (int)d[7]};
            }
            int gm[4];
#pragma unroll
            for (int r = 0; r < 4; r++) {
                int mrow = mt + q * 4 + r;
                gm[r] = (mrow < cnt) ? (int)lists[b * MDIM + mrow] : -1;
            }
#pragma unroll
            for (int ntile = 0; ntile < 8; ntile++) {
                int t = t0 + ntile * 16 + col;
                const unsigned char* brow = tf8 + (size_t)(b * TDIM + t) * DDIM;
                f32x4 acc = (f32x4){0.f, 0.f, 0.f, 0.f};
#pragma unroll
                for (int kc = 0; kc < 2; kc++) {
                    uint4 lo = *(const uint4*)(brow + kc * 128 + q * 32);
                    uint4 hi = *(const uint4*)(brow + kc * 128 + q * 32 + 16);
                    i32x8 bf = (i32x8){(int)lo.x, (int)lo.y, (int)lo.z, (int)lo.w,
                                       (int)hi.x, (int)hi.y, (int)hi.z, (int)hi.w};
                    acc = __builtin_amdgcn_mfma_scale_f32_16x16x128_f8f6f4(
                        af[kc], bf, acc, 0, 0, 0, 0x7F7F7F7F, 0, 0x7F7F7F7F);
                }
                int pmv = tpm[b * TDIM + t];
#pragma unroll
                for (int r = 0; r < 4; r++) {
                    if (gm[r] >= 0)
                        outP[(size_t)gm[r] * TDIM + t] = pmv ? acc[r] : NEGV;
                }
            }
        }
        return;
    }

    // ------------------- lemma MX-fp8 GEMM (R12/R14 config) -------------------
    const int bx = blockIdx.x - NLM;
    const int etile = bx * 128;
    const int wm = w & 1;      // m-half (64 rows)
    const int wn = w >> 1;     // n-half (32 of the 64-wide n-tile)

    // ---- stage A once: 64 fragment-ordered regions, 16 per wave ----
#pragma unroll
    for (int i = 0; i < 16; i++) {
        int r = w * 16 + i;
        int j = r & 1, kc = (r >> 1) & 3, mi = (r >> 3) & 3, am = r >> 5;
        int row = am * 64 + mi * 16 + col;
        int e = etile + row;
        int id = (e < E) ? ((kc < 2) ? scope[e] : goal[e]) : 0;
        gl2lds16(tf8 + (size_t)id * DDIM + (kc & 1) * 128 + q * 32 + j * 16,
                 &sA[r * 1024]);
    }
    __syncthreads();   // the ONLY barrier before the reduction

    float lem[16];
#pragma unroll
    for (int i = 0; i < 16; i++) lem[i] = 0.f;

    const unsigned char* wbase = wp8 + lane * 32;

#define LOADB(s, buf)                                                          \
    {                                                                          \
        _Pragma("unroll")                                                      \
        for (int ni_ = 0; ni_ < 2; ni_++) {                                    \
            size_t f_ = (size_t)(((s) * 2 + wn) * 2 + ni_) * 2048;             \
            uint4 lo_ = *(const uint4*)(wbase + f_);                           \
            uint4 hi_ = *(const uint4*)(wbase + f_ + 16);                      \
            bgb[buf][ni_] = (i32x8){(int)lo_.x, (int)lo_.y, (int)lo_.z,        \
                (int)lo_.w, (int)hi_.x, (int)hi_.y, (int)hi_.z, (int)hi_.w};   \
            lo_ = *(const uint4*)(wbase + WARR + f_);                          \
            hi_ = *(const uint4*)(wbase + WARR + f_ + 16);                     \
            bvb[buf][ni_] = (i32x8){(int)lo_.x, (int)lo_.y, (int)lo_.z,        \
                (int)lo_.w, (int)hi_.x, (int)hi_.y, (int)hi_.z, (int)hi_.w};   \
        }                                                                      \
    }

    i32x8 bgb[2][2], bvb[2][2];
    LOADB(0, 0)

    for (int nt = 0; nt < 16; nt++) {
        f32x4 accG[4][2], accV[4][2];
#pragma unroll
        for (int mi = 0; mi < 4; mi++)
#pragma unroll
            for (int ni = 0; ni < 2; ni++) {
                accG[mi][ni] = (f32x4){0.f, 0.f, 0.f, 0.f};
                accV[mi][ni] = (f32x4){0.f, 0.f, 0.f, 0.f};
            }
#pragma unroll
        for (int kc = 0; kc < 4; kc++) {
            const int cur = kc & 1, nxt = cur ^ 1;
            LOADB(nt * 4 + kc + 1, nxt)        // prefetch next step's B
#pragma unroll
            for (int mi = 0; mi < 4; mi++) {
                int rb = ((wm * 4 + mi) * 4 + kc) * 2;
                uint4 lo = *(const uint4*)(&sA[rb * 1024 + lane * 16]);
                uint4 hi = *(const uint4*)(&sA[(rb + 1) * 1024 + lane * 16]);
                i32x8 af = (i32x8){(int)lo.x, (int)lo.y, (int)lo.z, (int)lo.w,
                                   (int)hi.x, (int)hi.y, (int)hi.z, (int)hi.w};
#pragma unroll
                for (int ni = 0; ni < 2; ni++) {
                    accG[mi][ni] = __builtin_amdgcn_mfma_scale_f32_16x16x128_f8f6f4(
                        af, bgb[cur][ni], accG[mi][ni], 0, 0, 0,
                        0x7F7F7F7F, 0, 0x7F7F7F7F);
                    accV[mi][ni] = __builtin_amdgcn_mfma_scale_f32_16x16x128_f8f6f4(
                        af, bvb[cur][ni], accV[mi][ni], 0, 0, 0,
                        0x7F7F7F7F, 0, 0x7F7F7F7F);
                }
            }
        }
        // epilogue: lem += silu(G)*V*Wo[n].  exp+rcpf (R14-proven).
#pragma unroll
        for (int ni = 0; ni < 2; ni++) {
            float wo = Wo[nt * 64 + wn * 32 + ni * 16 + col];
#pragma unroll
            for (int mi = 0; mi < 4; mi++)
#pragma unroll
                for (int r = 0; r < 4; r++) {
                    float g = accG[mi][ni][r];
                    float v = accV[mi][ni][r];
                    float s = g * __builtin_amdgcn_rcpf(1.f + __expf(-g));
                    lem[mi * 4 + r] += s * v * wo;
                }
        }
    }
    // reduce across the 16 N-cols, then across the 2 n-wave halves
#pragma unroll
    for (int i = 0; i < 16; i++) {
        float v = lem[i];
        for (int off = 8; off > 0; off >>= 1) v += __shfl_xor(v, off, 16);
        if (col == 0) {
            int row = wm * 64 + (i >> 2) * 16 + q * 4 + (i & 3);
            sRed[wn * 128 + row] = v;
        }
    }
    __syncthreads();
    if (tid < 128) {
        int e = etile + tid;
        if (e < E) outLem[e] = sRed[tid] + sRed[128 + tid];
    }
}

extern "C" void kernel_launch(void* const* d_in, const int* in_sizes, int n_in,
                              void* d_out, int out_size, void* d_ws, size_t ws_size,
                              hipStream_t stream) {
    const float* tok = (const float*)d_in[0];
    const float* Wg  = (const float*)d_in[1];
    const float* Wv  = (const float*)d_in[2];
    const float* Wo  = (const float*)d_in[3];
    const int* edge = (const int*)d_in[4];
    const int* lmi  = (const int*)d_in[5];
    const int* bp   = (const int*)d_in[6];
    const int* tpm  = (const int*)d_in[7];
    const int E = in_sizes[4] / 2;           // 100000
    float* out = (float*)d_out;

    // workspace layout (~5.2 MB)
    unsigned char* tf8 = (unsigned char*)d_ws;                 // 4 MB
    unsigned char* wp8 = tf8 + (size_t)NROWS * DDIM;           // 1 MB (G+V)
    int* counts = (int*)(wp8 + 2 * WARR);                      // 128 B
    unsigned short* lists = (unsigned short*)(counts + 32);    // 128 KB

    prep_all<<<dim3(4609), dim3(256), 0, stream>>>(
        tok, Wg, Wv, bp, tf8, wp8, counts, lists);
    int nLemBlocks = (E + 127) / 128;        // 782
    fused_main<<<dim3(NLM + nLemBlocks), dim3(256), 0, stream>>>(
        tf8, wp8, Wo, edge, edge + E, out, E,
        tok, lmi, counts, lists, tpm, out + E);
}

// Round 12
// 228.662 us; speedup vs baseline: 1.2218x; 1.0056x over previous
//
#include <hip/hip_runtime.h>
#include <hip/hip_bf16.h>

typedef __bf16 bf16x8 __attribute__((ext_vector_type(8)));
typedef int   i32x8 __attribute__((ext_vector_type(8)));
typedef float f32x4 __attribute__((ext_vector_type(4)));

#define KDIM 512
#define NDIM 1024
#define DDIM 256
#define TDIM 512
#define MDIM 2048
#define NROWS 16384          // B*T type_flat rows
#define NEGV -1e10f
#define NLM 128              // lm blocks fused at the front of the main grid
#define WARR 524288          // byte offset of V-array in permuted weights

__device__ __forceinline__ unsigned int pk8(float a, float b, float c, float d) {
    unsigned int p = (unsigned int)__builtin_amdgcn_cvt_pk_fp8_f32(a, b, 0, 0);
    return (unsigned int)__builtin_amdgcn_cvt_pk_fp8_f32(c, d, (int)p, 1);
}

typedef const __attribute__((address_space(1))) unsigned int* gas_p;
typedef __attribute__((address_space(3))) unsigned int* las_p;
__device__ __forceinline__ void gl2lds16(const void* g, void* l) {
    __builtin_amdgcn_global_load_lds((gas_p)g, (las_p)l, 16, 0, 0);
}

// ---------------------------------------------------------------------------
// prep_all: one launch, three roles by blockIdx.  (R14/R16-proven, exact
// R25-verified form — R26 showed prep structure is perf-invariant.)
// ---------------------------------------------------------------------------
__global__ void prep_all(const float* __restrict__ tok,
                         const float* __restrict__ Wg,
                         const float* __restrict__ Wv,
                         const int* __restrict__ bp,
                         unsigned char* __restrict__ tf8,
                         unsigned char* __restrict__ wp8,
                         int* __restrict__ counts,
                         unsigned short* __restrict__ lists) {
    const int bid = blockIdx.x;
    const int tid = threadIdx.x;
    if (bid < 4096) {
        int g = (bid * 256 + tid) * 4;
        int i = g >> 8, c = g & 255;
        float4 v = *(const float4*)(tok + (size_t)i * 1024 + c);
        *(unsigned int*)(tf8 + g) = pk8(v.x, v.y, v.z, v.w);
    } else if (bid < 4608) {
        __shared__ float tg[32][33];
        __shared__ float tv[32][33];
        int pb = bid - 4096;
        int n0 = (pb & 31) * 32, k0 = (pb >> 5) * 32;
        {
            int kk = tid >> 3, nn = (tid & 7) * 4;
            float4 g = *(const float4*)(Wg + (size_t)(k0 + kk) * NDIM + n0 + nn);
            float4 v = *(const float4*)(Wv + (size_t)(k0 + kk) * NDIM + n0 + nn);
            tg[kk][nn] = g.x; tg[kk][nn + 1] = g.y; tg[kk][nn + 2] = g.z; tg[kk][nn + 3] = g.w;
            tv[kk][nn] = v.x; tv[kk][nn + 1] = v.y; tv[kk][nn + 2] = v.z; tv[kk][nn + 3] = v.w;
        }
        __syncthreads();
        int nn2 = tid >> 3, kk2 = (tid & 7) * 4;
        unsigned int pg = pk8(tg[kk2][nn2], tg[kk2 + 1][nn2],
                              tg[kk2 + 2][nn2], tg[kk2 + 3][nn2]);
        unsigned int pv = pk8(tv[kk2][nn2], tv[kk2 + 1][nn2],
                              tv[kk2 + 2][nn2], tv[kk2 + 3][nn2]);
        int n = n0 + nn2, k = k0 + kk2;
        int nt = n >> 6, wn = (n >> 5) & 1, ni = (n >> 4) & 1, cp = n & 15;
        int kc = k >> 7, rem = k & 127, qq = rem >> 5, hh = (rem >> 4) & 1, bb = rem & 15;
        int frag = ((nt * 4 + kc) * 2 + wn) * 2 + ni;
        size_t off = (size_t)frag * 2048 + (qq * 16 + cp) * 32 + hh * 16 + bb;
        *(unsigned int*)(wp8 + off) = pg;
        *(unsigned int*)(wp8 + WARR + off) = pv;
    } else {
        __shared__ int c[32];
        if (tid < 32) c[tid] = 0;
        __syncthreads();
        for (int m = tid; m < MDIM; m += 256) {
            int b = bp[m];
            int pos = atomicAdd(&c[b], 1);
            lists[b * MDIM + pos] = (unsigned short)m;
        }
        __syncthreads();
        if (tid < 32) counts[tid] = c[tid];
    }
}

// ---------------------------------------------------------------------------
// fused_main — R28: round-0 verified body + ONE change: per-block nt-PHASE
// ROTATION (nt0 = (bx*5)&15; nt visits (nt0+t)&15).  Pure index arithmetic:
// zero extra live registers, zero traffic change, commutative lem order.
// Theory: the 2 co-resident blocks/CU launch in the same dispatch burst and
// run IDENTICAL code on IDENTICAL wp8 addresses -> their VMEM bursts and
// trans-heavy epilogues coincide; each wave stalls exactly when its SIMD
// partner stalls (the 43% neither-pipe signature, invariant to occupancy).
// Rotation anti-phases the blocks so one wave's epilogue overlaps the
// other's MFMA cluster.  R23 could NOT rule this out (its 3-wave null was
// confounded by a degraded per-wave structure).
// SESSION LEDGER (R18-R27, counter-verified): occupancy-at-no-spill neutral
// (R23); caps <=170 spill 64-260MB scratch (R18/19/20/24); s_setprio poison
// (R22); manual af pipeline neutral (R21); 32x32x64 shape worse, ILP loss
// (R27); prep/launch reorg neutral, ~86us is harness-fixed (R26).
// ---------------------------------------------------------------------------
__launch_bounds__(256, 2)
__global__ void fused_main(const unsigned char* __restrict__ tf8,
                           const unsigned char* __restrict__ wp8,
                           const float* __restrict__ Wo,
                           const int* __restrict__ scope,
                           const int* __restrict__ goal,
                           float* __restrict__ outLem, int E,
                           const float* __restrict__ tok,
                           const int* __restrict__ lmi,
                           const int* __restrict__ counts,
                           const unsigned short* __restrict__ lists,
                           const int* __restrict__ tpm,
                           float* __restrict__ outP) {
    __shared__ unsigned char sA[64 * 1024];   // 64 regions x 1 KB, key (am,mi,kc,j)
    __shared__ float sRed[256];

    const int tid = threadIdx.x;
    const int lane = tid & 63;
    const int w = tid >> 6;
    const int col = lane & 15;
    const int q = lane >> 4;

    if ((int)blockIdx.x < NLM) {
        // ------------- lm_preds gather-GEMM, MX-fp8 (R14-proven) -------------
        const int lb = blockIdx.x;
        const int b = lb & 31;
        const int t0 = (lb >> 5) * 128;
        const int cnt = counts[b];
        for (int mt = w * 16; mt < cnt; mt += 64) {
            int mc = mt + col;
            int aid = lists[b * MDIM + (mc < cnt ? mc : cnt - 1)];
            const float* arow = tok + (size_t)lmi[aid] * DDIM;
            i32x8 af[2];
#pragma unroll
            for (int kc = 0; kc < 2; kc++) {
                unsigned int d[8];
#pragma unroll
                for (int j = 0; j < 8; j++) {
                    float4 v = *(const float4*)(arow + kc * 128 + q * 32 + j * 4);
                    d[j] = pk8(v.x, v.y, v.z, v.w);
                }
                af[kc] = (i32x8){(int)d[0], (int)d[1], (int)d[2], (int)d[3],
                                 (int)d[4], (int)d[5], (int)d[6], (int)d[7]};
            }
            int gm[4];
#pragma unroll
            for (int r = 0; r < 4; r++) {
                int mrow = mt + q * 4 + r;
                gm[r] = (mrow < cnt) ? (int)lists[b * MDIM + mrow] : -1;
            }
#pragma unroll
            for (int ntile = 0; ntile < 8; ntile++) {
                int t = t0 + ntile * 16 + col;
                const unsigned char* brow = tf8 + (size_t)(b * TDIM + t) * DDIM;
                f32x4 acc = (f32x4){0.f, 0.f, 0.f, 0.f};
#pragma unroll
                for (int kc = 0; kc < 2; kc++) {
                    uint4 lo = *(const uint4*)(brow + kc * 128 + q * 32);
                    uint4 hi = *(const uint4*)(brow + kc * 128 + q * 32 + 16);
                    i32x8 bf = (i32x8){(int)lo.x, (int)lo.y, (int)lo.z, (int)lo.w,
                                       (int)hi.x, (int)hi.y, (int)hi.z, (int)hi.w};
                    acc = __builtin_amdgcn_mfma_scale_f32_16x16x128_f8f6f4(
                        af[kc], bf, acc, 0, 0, 0, 0x7F7F7F7F, 0, 0x7F7F7F7F);
                }
                int pmv = tpm[b * TDIM + t];
#pragma unroll
                for (int r = 0; r < 4; r++) {
                    if (gm[r] >= 0)
                        outP[(size_t)gm[r] * TDIM + t] = pmv ? acc[r] : NEGV;
                }
            }
        }
        return;
    }

    // ------------------- lemma MX-fp8 GEMM (R12/R14 config) -------------------
    const int bx = blockIdx.x - NLM;
    const int etile = bx * 128;
    const int wm = w & 1;      // m-half (64 rows)
    const int wn = w >> 1;     // n-half (32 of the 64-wide n-tile)

    // ---- stage A once: 64 fragment-ordered regions, 16 per wave ----
#pragma unroll
    for (int i = 0; i < 16; i++) {
        int r = w * 16 + i;
        int j = r & 1, kc = (r >> 1) & 3, mi = (r >> 3) & 3, am = r >> 5;
        int row = am * 64 + mi * 16 + col;
        int e = etile + row;
        int id = (e < E) ? ((kc < 2) ? scope[e] : goal[e]) : 0;
        gl2lds16(tf8 + (size_t)id * DDIM + (kc & 1) * 128 + q * 32 + j * 16,
                 &sA[r * 1024]);
    }
    __syncthreads();   // the ONLY barrier before the reduction

    float lem[16];
#pragma unroll
    for (int i = 0; i < 16; i++) lem[i] = 0.f;

    const unsigned char* wbase = wp8 + lane * 32;

#define LOADB(s, buf)                                                          \
    {                                                                          \
        _Pragma("unroll")                                                      \
        for (int ni_ = 0; ni_ < 2; ni_++) {                                    \
            size_t f_ = (size_t)(((s) * 2 + wn) * 2 + ni_) * 2048;             \
            uint4 lo_ = *(const uint4*)(wbase + f_);                           \
            uint4 hi_ = *(const uint4*)(wbase + f_ + 16);                      \
            bgb[buf][ni_] = (i32x8){(int)lo_.x, (int)lo_.y, (int)lo_.z,        \
                (int)lo_.w, (int)hi_.x, (int)hi_.y, (int)hi_.z, (int)hi_.w};   \
            lo_ = *(const uint4*)(wbase + WARR + f_);                          \
            hi_ = *(const uint4*)(wbase + WARR + f_ + 16);                     \
            bvb[buf][ni_] = (i32x8){(int)lo_.x, (int)lo_.y, (int)lo_.z,        \
                (int)lo_.w, (int)hi_.x, (int)hi_.y, (int)hi_.z, (int)hi_.w};   \
        }                                                                      \
    }

    i32x8 bgb[2][2], bvb[2][2];

    // R28: per-block phase rotation — co-resident blocks start at different
    // nt so their VMEM/epilogue/MFMA phases interleave instead of colliding.
    const int nt0 = (bx * 5) & 15;
    LOADB(nt0 * 4, 0)

    for (int t = 0; t < 16; t++) {
        const int nt = (nt0 + t) & 15;
        f32x4 accG[4][2], accV[4][2];
#pragma unroll
        for (int mi = 0; mi < 4; mi++)
#pragma unroll
            for (int ni = 0; ni < 2; ni++) {
                accG[mi][ni] = (f32x4){0.f, 0.f, 0.f, 0.f};
                accV[mi][ni] = (f32x4){0.f, 0.f, 0.f, 0.f};
            }
#pragma unroll
        for (int kc = 0; kc < 4; kc++) {
            const int cur = kc & 1, nxt = cur ^ 1;
            // prefetch next step's B: same nt for kc<3, else next nt's kc=0
            const int snx = (kc < 3) ? (nt * 4 + kc + 1)
                                     : (((nt0 + t + 1) & 15) * 4);
            LOADB(snx, nxt)
#pragma unroll
            for (int mi = 0; mi < 4; mi++) {
                int rb = ((wm * 4 + mi) * 4 + kc) * 2;
                uint4 lo = *(const uint4*)(&sA[rb * 1024 + lane * 16]);
                uint4 hi = *(const uint4*)(&sA[(rb + 1) * 1024 + lane * 16]);
                i32x8 af = (i32x8){(int)lo.x, (int)lo.y, (int)lo.z, (int)lo.w,
                                   (int)hi.x, (int)hi.y, (int)hi.z, (int)hi.w};
#pragma unroll
                for (int ni = 0; ni < 2; ni++) {
                    accG[mi][ni] = __builtin_amdgcn_mfma_scale_f32_16x16x128_f8f6f4(
                        af, bgb[cur][ni], accG[mi][ni], 0, 0, 0,
                        0x7F7F7F7F, 0, 0x7F7F7F7F);
                    accV[mi][ni] = __builtin_amdgcn_mfma_scale_f32_16x16x128_f8f6f4(
                        af, bvb[cur][ni], accV[mi][ni], 0, 0, 0,
                        0x7F7F7F7F, 0, 0x7F7F7F7F);
                }
            }
        }
        // epilogue: lem += silu(G)*V*Wo[n].  exp+rcpf (R14-proven).
#pragma unroll
        for (int ni = 0; ni < 2; ni++) {
            float wo = Wo[nt * 64 + wn * 32 + ni * 16 + col];
#pragma unroll
            for (int mi = 0; mi < 4; mi++)
#pragma unroll
                for (int r = 0; r < 4; r++) {
                    float g = accG[mi][ni][r];
                    float v = accV[mi][ni][r];
                    float s = g * __builtin_amdgcn_rcpf(1.f + __expf(-g));
                    lem[mi * 4 + r] += s * v * wo;
                }
        }
    }
    // reduce across the 16 N-cols, then across the 2 n-wave halves
#pragma unroll
    for (int i = 0; i < 16; i++) {
        float v = lem[i];
        for (int off = 8; off > 0; off >>= 1) v += __shfl_xor(v, off, 16);
        if (col == 0) {
            int row = wm * 64 + (i >> 2) * 16 + q * 4 + (i & 3);
            sRed[wn * 128 + row] = v;
        }
    }
    __syncthreads();
    if (tid < 128) {
        int e = etile + tid;
        if (e < E) outLem[e] = sRed[tid] + sRed[128 + tid];
    }
}

extern "C" void kernel_launch(void* const* d_in, const int* in_sizes, int n_in,
                              void* d_out, int out_size, void* d_ws, size_t ws_size,
                              hipStream_t stream) {
    const float* tok = (const float*)d_in[0];
    const float* Wg  = (const float*)d_in[1];
    const float* Wv  = (const float*)d_in[2];
    const float* Wo  = (const float*)d_in[3];
    const int* edge = (const int*)d_in[4];
    const int* lmi  = (const int*)d_in[5];
    const int* bp   = (const int*)d_in[6];
    const int* tpm  = (const int*)d_in[7];
    const int E = in_sizes[4] / 2;           // 100000
    float* out = (float*)d_out;

    // workspace layout (~5.2 MB)
    unsigned char* tf8 = (unsigned char*)d_ws;                 // 4 MB
    unsigned char* wp8 = tf8 + (size_t)NROWS * DDIM;           // 1 MB (G+V)
    int* counts = (int*)(wp8 + 2 * WARR);                      // 128 B
    unsigned short* lists = (unsigned short*)(counts + 32);    // 128 KB

    prep_all<<<dim3(4609), dim3(256), 0, stream>>>(
        tok, Wg, Wv, bp, tf8, wp8, counts, lists);
    int nLemBlocks = (E + 127) / 128;        // 782
    fused_main<<<dim3(NLM + nLemBlocks), dim3(256), 0, stream>>>(
        tf8, wp8, Wo, edge, edge + E, out, E,
        tok, lmi, counts, lists, tpm, out + E);
}